// Round 1
// baseline (1726.645 us; speedup 1.0000x reference)
//
#include <hip/hip_runtime.h>
#include <math.h>

// ---------------- dims / constants ----------------
#define EPS_Q 1e-4
#define TOLC  1e-3

// ws layout: doubles first
#define OFF_D22   0        // [32][32]
#define OFF_RINV  1024     // [32][32]
#define OFF_VR    2048     // [160][32]
#define OFF_T1    7168     // [160][32]
#define OFF_H     12288    // [160][160]
#define OFF_E     37888    // [64][64]
#define OFF_EI    41984    // [64][64]
#define OFF_TMP   46080    // [64][64]
#define OFF_TMP2  50176    // [64][64]
#define D_END     54272    // doubles
// float blob after doubles (byte offset 434176, 16B aligned):
// F_WXT  = 0      : Wx k-major f4-transposed [32 chunks][64 rows][4] = 8192 floats
// F_WYT  = 8192   : Wy k-major f4-transposed [32 chunks][32 rows][4] = 4096 floats
// F_D11  = 12288  : [32][32] strictly-lower, pre-scaled by K/Lam_i   = 1024
// F_WA   = 13312  : [32][96] rows [C1(64)|D12(32)] * (K/Lam_r)       = 3072
// K = 2*log2(e): chain state v lives in exp2 domain (saves mul on critical path)

// ================= prep 1: D22, R_cal^-1, vec_r, T1 =================
__global__ __launch_bounds__(256, 1) void prep1(
    const float* __restrict__ B2, const float* __restrict__ C2,
    const float* __restrict__ D12, const float* __restrict__ L,
    const float* __restrict__ U, const float* __restrict__ D21,
    const float* __restrict__ gam, double* __restrict__ wsd)
{
  __shared__ double aug[32][65];
  __shared__ double sFac[32];
  __shared__ int sPiv;
  const int tid = threadIdx.x;
  const double g = (double)gam[0];
  double* D22d = wsd + OFF_D22;

  for (int idx = tid; idx < 1024; idx += 256) {
    int i = idx >> 5, j = idx & 31;
    double s = (i == j) ? (g + 1.0) : 0.0;
    for (int k = 0; k < 32; ++k) s += (double)L[k*32+i] * (double)L[k*32+j];
    s += (double)U[i*32+j] - (double)U[j*32+i];
    D22d[idx] = s;
  }
  __syncthreads();
  for (int idx = tid; idx < 1024; idx += 256) {
    int i = idx >> 5, j = idx & 31;
    double s = (i == j) ? (-2.0 * g) : 0.0;
    s += D22d[i*32+j] + D22d[j*32+i];
    double q = 0.0;
    for (int k = 0; k < 32; ++k) q += D22d[k*32+i] * D22d[k*32+j];
    aug[i][j] = s - EPS_Q * q;
    aug[i][32+j] = (i == j) ? 1.0 : 0.0;
  }
  __syncthreads();
  for (int k = 0; k < 32; ++k) {
    if (tid < 64) {
      float mv = -1.f; int mi = k;
      if (tid < 32 && tid >= k) { mv = (float)fabs(aug[tid][k]); mi = tid; }
      #pragma unroll
      for (int o = 32; o; o >>= 1) {
        float ov = __shfl_xor(mv, o); int oi = __shfl_xor(mi, o);
        if (ov > mv) { mv = ov; mi = oi; }
      }
      if (tid == 0) sPiv = mi;
    }
    __syncthreads();
    int p = sPiv;
    if (p != k) for (int c = tid; c < 64; c += 256) { double t1 = aug[k][c]; aug[k][c] = aug[p][c]; aug[p][c] = t1; }
    __syncthreads();
    double pinv = 1.0 / aug[k][k];
    if (tid < 32 && tid != k) sFac[tid] = aug[tid][k];
    __syncthreads();
    for (int c = tid; c < 64; c += 256) aug[k][c] *= pinv;
    __syncthreads();
    for (int idx = tid; idx < 2048; idx += 256) {
      int r = idx >> 6, c = idx & 63;
      if (r != k) aug[r][c] -= sFac[r] * aug[k][c];
    }
    __syncthreads();
  }
  double* Rinv = wsd + OFF_RINV;
  for (int idx = tid; idx < 1024; idx += 256) Rinv[idx] = aug[idx >> 5][32 + (idx & 31)];

  double* vr = wsd + OFF_VR;
  for (int idx = tid; idx < 64*32; idx += 256) {
    int p = idx >> 5, k = idx & 31;
    double q = 0.0;
    for (int m = 0; m < 32; ++m) q += D22d[m*32+k] * (double)C2[m*64+p];
    vr[p*32+k] = (double)C2[k*64+p] - EPS_Q * q;
  }
  for (int idx = tid; idx < 32*32; idx += 256) {
    int p = idx >> 5, k = idx & 31;
    double q = 0.0;
    for (int m = 0; m < 32; ++m) q += D22d[m*32+k] * (double)D21[m*32+p];
    vr[(64+p)*32+k] = (double)D21[k*32+p] - EPS_Q * q - (double)D12[p*32+k];
  }
  for (int idx = tid; idx < 64*32; idx += 256) {
    int p = idx >> 5, k = idx & 31;
    vr[(96+p)*32+k] = (double)B2[p*32+k];
  }
  __syncthreads();
  double* T1 = wsd + OFF_T1;
  for (int idx = tid; idx < 160*32; idx += 256) {
    int p = idx >> 5, k2 = idx & 31;
    double s = 0.0;
    for (int k = 0; k < 32; ++k) s += vr[p*32+k] * Rinv[k*32+k2];
    T1[idx] = s;
  }
}

// ================= prep 2: H = X^T X + tol I + psi_r - psi_q =================
__global__ __launch_bounds__(256, 1) void prep2(
    const float* __restrict__ X, const float* __restrict__ C2,
    const float* __restrict__ D21, double* __restrict__ wsd)
{
  const double* vr = wsd + OFF_VR;
  const double* T1 = wsd + OFF_T1;
  double* H = wsd + OFF_H;
  int bi = blockIdx.x / 10, bj = blockIdx.x % 10;
  int i = bi*16 + (threadIdx.x >> 4);
  int j = bj*16 + (threadIdx.x & 15);
  double s = (i == j) ? TOLC : 0.0;
  for (int k = 0; k < 160; ++k) s += (double)X[k*160+i] * (double)X[k*160+j];
  double pr = 0.0;
  for (int k = 0; k < 32; ++k) pr += T1[i*32+k] * vr[j*32+k];
  s += pr;
  if (i < 96 && j < 96) {
    double vq = 0.0;
    for (int k = 0; k < 32; ++k) {
      double a = (i < 64) ? (double)C2[k*64+i] : (double)D21[k*32+(i-64)];
      double b = (j < 64) ? (double)C2[k*64+j] : (double)D21[k*32+(j-64)];
      vq += a*b;
    }
    s += EPS_Q * vq;
  }
  H[i*160+j] = s;
}

// ================= prep 3: E^-1 (GJ fp32 + 2x fp64 Newton), weight blob =================
__global__ __launch_bounds__(256, 1) void prep3(
    const float* __restrict__ Y, const float* __restrict__ B2,
    const float* __restrict__ C2, const float* __restrict__ D12,
    const float* __restrict__ D21, double* __restrict__ wsd)
{
  __shared__ float aug[64][130];
  __shared__ float sFac[64];
  __shared__ int sPiv;
  const int tid = threadIdx.x;
  double* H   = wsd + OFF_H;
  double* Ed  = wsd + OFF_E;
  double* Ei  = wsd + OFF_EI;
  double* Tm  = wsd + OFF_TMP;
  double* Tm2 = wsd + OFF_TMP2;
  double* D22d = wsd + OFF_D22;
  float* fb = (float*)(wsd + D_END);
  const double KS = 2.8853900817779268;   // 2*log2(e)

  for (int idx = tid; idx < 4096; idx += 256) {
    int i = idx >> 6, j = idx & 63;
    double e = 0.5*(H[i*160+j] + H[(96+i)*160+(96+j)] + (double)Y[i*64+j] - (double)Y[j*64+i]);
    Ed[idx] = e;
    aug[i][j] = (float)e;
    aug[i][64+j] = (i == j) ? 1.f : 0.f;
  }
  __syncthreads();
  for (int k = 0; k < 64; ++k) {
    if (tid < 64) {
      float mv = -1.f; int mi = k;
      if (tid >= k) { mv = fabsf(aug[tid][k]); mi = tid; }
      #pragma unroll
      for (int o = 32; o; o >>= 1) {
        float ov = __shfl_xor(mv, o); int oi = __shfl_xor(mi, o);
        if (ov > mv) { mv = ov; mi = oi; }
      }
      if (tid == 0) sPiv = mi;
    }
    __syncthreads();
    int p = sPiv;
    if (p != k) for (int c = tid; c < 128; c += 256) { float t1 = aug[k][c]; aug[k][c] = aug[p][c]; aug[p][c] = t1; }
    __syncthreads();
    float pinv = 1.0f / aug[k][k];
    if (tid < 64 && tid != k) sFac[tid] = aug[tid][k];
    __syncthreads();
    for (int c = tid; c < 128; c += 256) aug[k][c] *= pinv;
    __syncthreads();
    for (int idx = tid; idx < 64*128; idx += 256) {
      int r = idx >> 7, c = idx & 127;
      if (r != k) aug[r][c] -= sFac[r] * aug[k][c];
    }
    __syncthreads();
  }
  for (int idx = tid; idx < 4096; idx += 256) Ei[idx] = (double)aug[idx >> 6][64 + (idx & 63)];
  __syncthreads();
  for (int it = 0; it < 2; ++it) {
    for (int idx = tid; idx < 4096; idx += 256) {
      int i = idx >> 6, j = idx & 63;
      double s = (i == j) ? 2.0 : 0.0;
      for (int k = 0; k < 64; ++k) s -= Ed[i*64+k] * Ei[k*64+j];
      Tm[idx] = s;
    }
    __syncthreads();
    for (int idx = tid; idx < 4096; idx += 256) {
      int i = idx >> 6, j = idx & 63;
      double s = 0.0;
      for (int k = 0; k < 64; ++k) s += Ei[i*64+k] * Tm[k*64+j];
      Tm2[idx] = s;
    }
    __syncthreads();
    for (int idx = tid; idx < 4096; idx += 256) Ei[idx] = Tm2[idx];
    __syncthreads();
  }
  // WxT: k-major f4-transposed [32 chunks][64 rows][4]
  for (int idx = tid; idx < 64*128; idx += 256) {
    int r = idx >> 7, col = idx & 127;
    double s = 0.0;
    if (col < 64)       { for (int k = 0; k < 64; ++k) s += Ei[r*64+k] * H[(96+k)*160 + col]; }
    else if (col < 96)  { int jj = col-64; for (int k = 0; k < 64; ++k) s += Ei[r*64+k] * H[(96+k)*160 + 64 + jj]; }
    else                { int jj = col-96; for (int k = 0; k < 64; ++k) s += Ei[r*64+k] * (double)B2[k*32+jj]; }
    fb[((col >> 2)*64 + r)*4 + (col & 3)] = (float)s;
  }
  // WyT: k-major f4-transposed [32 chunks][32 rows][4]; cols [C2(64)|D21(32)|D22(32)]
  for (int idx = tid; idx < 32*128; idx += 256) {
    int r = idx >> 7, col = idx & 127;
    float v;
    if (col < 64)      v = C2[r*64 + col];
    else if (col < 96) v = D21[r*32 + (col-64)];
    else               v = (float)D22d[r*32 + (col-96)];
    fb[8192 + ((col >> 2)*32 + r)*4 + (col & 3)] = v;
  }
  // D11' (strict lower, scaled by K/Lam_i) @ 12288  -- chain runs in exp2 domain
  for (int idx = tid; idx < 1024; idx += 256) {
    int i = idx >> 5, j = idx & 31;
    double li = 2.0 / H[(64+i)*160 + 64+i];
    fb[12288 + idx] = (j < i) ? (float)(-H[(64+i)*160 + 64+j] * li * KS) : 0.f;
  }
  // Wa = [C1 | D12] * (K/Lam_r), row-major [32][96] @ 13312
  for (int idx = tid; idx < 32*96; ++idx, idx += 255) {}
  for (int idx = tid; idx < 32*96; idx += 256) {
    int r = idx / 96, j = idx % 96;
    double li = 2.0 / H[(64+r)*160 + 64+r];
    double v = (j < 64) ? (-H[(64+r)*160 + j] * li) : ((double)D12[r*32 + (j-64)] * li);
    fb[13312 + idx] = (float)(v * KS);
  }
}

// ================= main recurrence =================
__device__ __forceinline__ float frcp(float x) {
#if __has_builtin(__builtin_amdgcn_rcpf)
  return __builtin_amdgcn_rcpf(x);
#else
  return 1.0f / x;
#endif
}
__device__ __forceinline__ float hsum4(float4 a) { return (a.x + a.y) + (a.z + a.w); }

// E=2: each 64-lane wave owns TWO elements (lanes 0-31 = elem A, 32-63 = elem B).
// Every chain instruction (exp2/rcp) now serves 2 elements; the per-step broadcast
// is ds_swizzle BitMode (and=0, or=j) = broadcast lane j within each 32-lane group
// (DS pipe, not VALU). Chain state v lives in the exp2 domain (weights pre-scaled
// by K=2*log2 e in prep3); w = 1 - 2*rcp(exp2(v)+1), folded as
// v' = fma(-2*d11[j], rcp_bcast, v + d11[j]).
// 1024 waves -> 1 wave/SIMD: chain stalls are filled by hand-weaving the
// chain-independent X/Y partial chunks into the swizzle latency windows.
// VGPR budget at 1 wave/SIMD is ~512, so full Wa row (24 f4) lives in registers.
__global__ __launch_bounds__(256, 1) void ren_main(
    const float* __restrict__ u_in, const float* __restrict__ x0,
    const double* __restrict__ wsd, float* __restrict__ out)
{
  __shared__ __align__(16) float sW[12288];      // WxT [32][64]f4 | WyT [32][32]f4
  __shared__ __align__(16) float sXU[4][2][132]; // per wave, per element: x64|w32|u32|pad4
  const float* fb = (const float*)(wsd + D_END);
  const int tid = threadIdx.x;
  {
    const float4* g4 = (const float4*)fb;
    float4* s4 = (float4*)sW;
    for (int i = tid; i < 3072; i += 256) s4[i] = g4[i];
  }
  const int wv = tid >> 6, l = tid & 63;
  const int sub = l >> 5, r = l & 31;
  const int e = blockIdx.x * 8 + wv * 2 + sub;   // this half-wave's element
  float* xu = &sXU[wv][sub][0];

  // Wa full row r in registers: 24 f4 (2-way broadcast loads across subs)
  float4 wa[24];
  {
    const float4* WaG = (const float4*)(fb + 13312);
    #pragma unroll
    for (int c = 0; c < 24; ++c) wa[c] = WaG[r*24 + c];
  }
  float d11[32], m2d[32];
  {
    const float4* DG = (const float4*)(fb + 12288);
    #pragma unroll
    for (int c = 0; c < 8; ++c) {
      float4 dv = DG[r*8 + c];
      d11[4*c+0] = dv.x; d11[4*c+1] = dv.y; d11[4*c+2] = dv.z; d11[4*c+3] = dv.w;
    }
    #pragma unroll
    for (int j = 0; j < 32; ++j) m2d[j] = -2.f * d11[j];
  }
  // x0 and u(t=0)
  xu[r]      = x0[(size_t)e*64 + r];
  xu[32 + r] = x0[(size_t)e*64 + 32 + r];
  xu[96 + r] = u_in[(size_t)e*8192 + r];
  __syncthreads();   // weights staged (once, outside t-loop)

  const float4* xu4  = (const float4*)xu;        // 33 f4: x 0-15 | w 16-23 | u 24-31
  const float4* WxT4 = (const float4*)sW;
  const float4* WyT4 = (const float4*)(sW + 8192);
  const float* uG = u_in + (size_t)e * 8192;
  float* oG = out + (size_t)e * 8192;

  for (int t = 0; t < 256; ++t) {
    const int tn = (t < 255) ? (t + 1) : 255;
    float unext = uG[tn*32 + r];                 // prefetch u_{t+1}
    // ---- A: a_r = Wa[r] . [x;u], full-k per lane (no shfl combine) ----
    float4 sA0 = make_float4(0.f,0.f,0.f,0.f), sA1 = make_float4(0.f,0.f,0.f,0.f);
    #pragma unroll
    for (int c = 0; c < 24; c += 2) {
      int xi0 = (c   < 16) ? c     : (c + 8);    // u chunks live at f4 24..31
      int xi1 = (c+1 < 16) ? (c+1) : (c + 9);
      float4 xv0 = xu4[xi0]; float4 xv1 = xu4[xi1];
      sA0.x = fmaf(wa[c].x, xv0.x, sA0.x);   sA0.y = fmaf(wa[c].y, xv0.y, sA0.y);
      sA0.z = fmaf(wa[c].z, xv0.z, sA0.z);   sA0.w = fmaf(wa[c].w, xv0.w, sA0.w);
      sA1.x = fmaf(wa[c+1].x, xv1.x, sA1.x); sA1.y = fmaf(wa[c+1].y, xv1.y, sA1.y);
      sA1.z = fmaf(wa[c+1].z, xv1.z, sA1.z); sA1.w = fmaf(wa[c+1].w, xv1.w, sA1.w);
    }
    float v = hsum4(sA0) + hsum4(sA1);           // v = K*a_r (exp2 domain)

    float4 P0 = make_float4(0.f,0.f,0.f,0.f);    // xn row r
    float4 P1 = make_float4(0.f,0.f,0.f,0.f);    // xn row 32+r
    float4 Q  = make_float4(0.f,0.f,0.f,0.f);    // y row r

// X chunk: weights 2-way broadcast across subs, operand per-sub (2 lines)
#define XCHUNK(c) { float4 xv = xu4[c]; \
      float4 w0 = WxT4[((c) << 6) + r]; float4 w1 = WxT4[((c) << 6) + 32 + r]; \
      P0.x = fmaf(w0.x, xv.x, P0.x); P0.y = fmaf(w0.y, xv.y, P0.y); \
      P0.z = fmaf(w0.z, xv.z, P0.z); P0.w = fmaf(w0.w, xv.w, P0.w); \
      P1.x = fmaf(w1.x, xv.x, P1.x); P1.y = fmaf(w1.y, xv.y, P1.y); \
      P1.z = fmaf(w1.z, xv.z, P1.z); P1.w = fmaf(w1.w, xv.w, P1.w); }
// shared-operand chunk (w / u regions): feeds X rows r, 32+r AND y row r
#define XYCHUNK(c) { float4 xv = xu4[c]; \
      float4 w0 = WxT4[((c) << 6) + r]; float4 w1 = WxT4[((c) << 6) + 32 + r]; \
      float4 wy = WyT4[((c) << 5) + r]; \
      P0.x = fmaf(w0.x, xv.x, P0.x); P0.y = fmaf(w0.y, xv.y, P0.y); \
      P0.z = fmaf(w0.z, xv.z, P0.z); P0.w = fmaf(w0.w, xv.w, P0.w); \
      P1.x = fmaf(w1.x, xv.x, P1.x); P1.y = fmaf(w1.y, xv.y, P1.y); \
      P1.z = fmaf(w1.z, xv.z, P1.z); P1.w = fmaf(w1.w, xv.w, P1.w); \
      Q.x  = fmaf(wy.x, xv.x, Q.x);  Q.y  = fmaf(wy.y, xv.y, Q.y); \
      Q.z  = fmaf(wy.z, xv.z, Q.z);  Q.w  = fmaf(wy.w, xv.w, Q.w); }
// chain step split around the swizzle latency window
#define CPRE(j) float E_##j = __builtin_exp2f(v); \
      float rr_##j = frcp(E_##j + 1.f); \
      float br_##j = __int_as_float(__builtin_amdgcn_ds_swizzle(__float_as_int(rr_##j), ((j) << 5)));
#define CPOST(j) v = fmaf(m2d[j], br_##j, v + d11[j]);

    // ---- serial chain, filler chunks woven into each swizzle window ----
    CPRE(0)  XCHUNK(0)   CPOST(0)
    CPRE(1)  XCHUNK(1)   CPOST(1)
    CPRE(2)  XCHUNK(2)   CPOST(2)
    CPRE(3)  XCHUNK(3)   CPOST(3)
    CPRE(4)  XCHUNK(4)   CPOST(4)
    CPRE(5)  XCHUNK(5)   CPOST(5)
    CPRE(6)  XCHUNK(6)   CPOST(6)
    CPRE(7)  XCHUNK(7)   CPOST(7)
    CPRE(8)  XCHUNK(8)   CPOST(8)
    CPRE(9)  XCHUNK(9)   CPOST(9)
    CPRE(10) XCHUNK(10)  CPOST(10)
    CPRE(11) XCHUNK(11)  CPOST(11)
    CPRE(12) XCHUNK(12)  CPOST(12)
    CPRE(13) XCHUNK(13)  CPOST(13)
    CPRE(14) XCHUNK(14)  CPOST(14)
    CPRE(15) XCHUNK(15)  CPOST(15)
    CPRE(16) XYCHUNK(24) CPOST(16)
    CPRE(17) XYCHUNK(25) CPOST(17)
    CPRE(18) XYCHUNK(26) CPOST(18)
    CPRE(19) XYCHUNK(27) CPOST(19)
    CPRE(20) XYCHUNK(28) CPOST(20)
    CPRE(21) XYCHUNK(29) CPOST(21)
    CPRE(22) XYCHUNK(30) CPOST(22)
    CPRE(23) XYCHUNK(31) CPOST(23)
    CPRE(24) CPOST(24)
    CPRE(25) CPOST(25)
    CPRE(26) CPOST(26)
    CPRE(27) CPOST(27)
    CPRE(28) CPOST(28)
    CPRE(29) CPOST(29)
    CPRE(30) CPOST(30)

    // ---- own w (v is final for lane r after step r-1) ----
    float Ef = __builtin_exp2f(v);
    float myw = 1.f - 2.f * frcp(Ef + 1.f);
    xu[64 + r] = myw;
    // ---- w chunks 16..23: feed X rows and y ----
    XYCHUNK(16) XYCHUNK(17) XYCHUNK(18) XYCHUNK(19)
    XYCHUNK(20) XYCHUNK(21) XYCHUNK(22) XYCHUNK(23)
    // ---- store xn rows ----
    xu[r]      = hsum4(P0);
    xu[32 + r] = hsum4(P1);
    // ---- Y xn chunks 0..15 ----
    #pragma unroll
    for (int c = 0; c < 16; ++c) {
      float4 xv = xu4[c];
      float4 wy = WyT4[(c << 5) + r];
      Q.x = fmaf(wy.x, xv.x, Q.x); Q.y = fmaf(wy.y, xv.y, Q.y);
      Q.z = fmaf(wy.z, xv.z, Q.z); Q.w = fmaf(wy.w, xv.w, Q.w);
    }
    float y = hsum4(Q);
    oG[t*32 + r] = y;                            // full wave: 2x128B contiguous
    xu[96 + r] = unext;                          // u_{t+1} (u_t fully consumed)

#undef XCHUNK
#undef XYCHUNK
#undef CPRE
#undef CPOST
  }
}

// ================= launch =================
extern "C" void kernel_launch(void* const* d_in, const int* in_sizes, int n_in,
                              void* d_out, int out_size, void* d_ws, size_t ws_size,
                              hipStream_t stream)
{
  const float* u_in = (const float*)d_in[0];
  const float* x0   = (const float*)d_in[1];
  const float* X    = (const float*)d_in[2];
  const float* Y    = (const float*)d_in[3];
  const float* B2   = (const float*)d_in[4];
  const float* C2   = (const float*)d_in[5];
  const float* D12  = (const float*)d_in[6];
  const float* L    = (const float*)d_in[7];   // D22_L
  const float* U    = (const float*)d_in[8];   // D22_U
  const float* D21  = (const float*)d_in[9];
  const float* gam  = (const float*)d_in[10];
  double* wsd = (double*)d_ws;
  float* out = (float*)d_out;

  hipLaunchKernelGGL(prep1, dim3(1), dim3(256), 0, stream, B2, C2, D12, L, U, D21, gam, wsd);
  hipLaunchKernelGGL(prep2, dim3(100), dim3(256), 0, stream, X, C2, D21, wsd);
  hipLaunchKernelGGL(prep3, dim3(1), dim3(256), 0, stream, Y, B2, C2, D12, D21, wsd);
  hipLaunchKernelGGL(ren_main, dim3(256), dim3(256), 0, stream, u_in, x0, wsd, out);
}

// Round 2
// 1675.149 us; speedup vs baseline: 1.0307x; 1.0307x over previous
//
#include <hip/hip_runtime.h>
#include <math.h>

// ---------------- dims / constants ----------------
#define EPS_Q 1e-4
#define TOLC  1e-3

// ws layout: doubles first
#define OFF_D22   0        // [32][32]
#define OFF_RINV  1024     // [32][32]
#define OFF_VR    2048     // [160][32]
#define OFF_T1    7168     // [160][32]
#define OFF_H     12288    // [160][160]
#define OFF_E     37888    // [64][64]
#define OFF_EI    41984    // [64][64]
#define OFF_TMP   46080    // [64][64]
#define OFF_TMP2  50176    // [64][64]
#define D_END     54272    // doubles
// float blob after doubles (byte offset 434176, 16B aligned):
// F_WXT  = 0      : Wx k-major f4-transposed [32 chunks][64 rows][4] = 8192 floats
// F_WYT  = 8192   : Wy k-major f4-transposed [32 chunks][32 rows][4] = 4096 floats
// F_D11  = 12288  : [32][32] strictly-lower, pre-scaled by K/Lam_i   = 1024
// F_WA   = 13312  : [32][96] rows [C1(64)|D12(32)] * (K/Lam_r)       = 3072
// K = 2*log2(e): chain state v lives in exp2 domain (saves ops on critical path)

// ================= prep 1: D22, R_cal^-1, vec_r, T1 =================
__global__ __launch_bounds__(256, 1) void prep1(
    const float* __restrict__ B2, const float* __restrict__ C2,
    const float* __restrict__ D12, const float* __restrict__ L,
    const float* __restrict__ U, const float* __restrict__ D21,
    const float* __restrict__ gam, double* __restrict__ wsd)
{
  __shared__ double aug[32][65];
  __shared__ double sFac[32];
  __shared__ int sPiv;
  const int tid = threadIdx.x;
  const double g = (double)gam[0];
  double* D22d = wsd + OFF_D22;

  for (int idx = tid; idx < 1024; idx += 256) {
    int i = idx >> 5, j = idx & 31;
    double s = (i == j) ? (g + 1.0) : 0.0;
    for (int k = 0; k < 32; ++k) s += (double)L[k*32+i] * (double)L[k*32+j];
    s += (double)U[i*32+j] - (double)U[j*32+i];
    D22d[idx] = s;
  }
  __syncthreads();
  for (int idx = tid; idx < 1024; idx += 256) {
    int i = idx >> 5, j = idx & 31;
    double s = (i == j) ? (-2.0 * g) : 0.0;
    s += D22d[i*32+j] + D22d[j*32+i];
    double q = 0.0;
    for (int k = 0; k < 32; ++k) q += D22d[k*32+i] * D22d[k*32+j];
    aug[i][j] = s - EPS_Q * q;
    aug[i][32+j] = (i == j) ? 1.0 : 0.0;
  }
  __syncthreads();
  for (int k = 0; k < 32; ++k) {
    if (tid < 64) {
      float mv = -1.f; int mi = k;
      if (tid < 32 && tid >= k) { mv = (float)fabs(aug[tid][k]); mi = tid; }
      #pragma unroll
      for (int o = 32; o; o >>= 1) {
        float ov = __shfl_xor(mv, o); int oi = __shfl_xor(mi, o);
        if (ov > mv) { mv = ov; mi = oi; }
      }
      if (tid == 0) sPiv = mi;
    }
    __syncthreads();
    int p = sPiv;
    if (p != k) for (int c = tid; c < 64; c += 256) { double t1 = aug[k][c]; aug[k][c] = aug[p][c]; aug[p][c] = t1; }
    __syncthreads();
    double pinv = 1.0 / aug[k][k];
    if (tid < 32 && tid != k) sFac[tid] = aug[tid][k];
    __syncthreads();
    for (int c = tid; c < 64; c += 256) aug[k][c] *= pinv;
    __syncthreads();
    for (int idx = tid; idx < 2048; idx += 256) {
      int r = idx >> 6, c = idx & 63;
      if (r != k) aug[r][c] -= sFac[r] * aug[k][c];
    }
    __syncthreads();
  }
  double* Rinv = wsd + OFF_RINV;
  for (int idx = tid; idx < 1024; idx += 256) Rinv[idx] = aug[idx >> 5][32 + (idx & 31)];

  double* vr = wsd + OFF_VR;
  for (int idx = tid; idx < 64*32; idx += 256) {
    int p = idx >> 5, k = idx & 31;
    double q = 0.0;
    for (int m = 0; m < 32; ++m) q += D22d[m*32+k] * (double)C2[m*64+p];
    vr[p*32+k] = (double)C2[k*64+p] - EPS_Q * q;
  }
  for (int idx = tid; idx < 32*32; idx += 256) {
    int p = idx >> 5, k = idx & 31;
    double q = 0.0;
    for (int m = 0; m < 32; ++m) q += D22d[m*32+k] * (double)D21[m*32+p];
    vr[(64+p)*32+k] = (double)D21[k*32+p] - EPS_Q * q - (double)D12[p*32+k];
  }
  for (int idx = tid; idx < 64*32; idx += 256) {
    int p = idx >> 5, k = idx & 31;
    vr[(96+p)*32+k] = (double)B2[p*32+k];
  }
  __syncthreads();
  double* T1 = wsd + OFF_T1;
  for (int idx = tid; idx < 160*32; idx += 256) {
    int p = idx >> 5, k2 = idx & 31;
    double s = 0.0;
    for (int k = 0; k < 32; ++k) s += vr[p*32+k] * Rinv[k*32+k2];
    T1[idx] = s;
  }
}

// ================= prep 2: H = X^T X + tol I + psi_r - psi_q =================
__global__ __launch_bounds__(256, 1) void prep2(
    const float* __restrict__ X, const float* __restrict__ C2,
    const float* __restrict__ D21, double* __restrict__ wsd)
{
  const double* vr = wsd + OFF_VR;
  const double* T1 = wsd + OFF_T1;
  double* H = wsd + OFF_H;
  int bi = blockIdx.x / 10, bj = blockIdx.x % 10;
  int i = bi*16 + (threadIdx.x >> 4);
  int j = bj*16 + (threadIdx.x & 15);
  double s = (i == j) ? TOLC : 0.0;
  for (int k = 0; k < 160; ++k) s += (double)X[k*160+i] * (double)X[k*160+j];
  double pr = 0.0;
  for (int k = 0; k < 32; ++k) pr += T1[i*32+k] * vr[j*32+k];
  s += pr;
  if (i < 96 && j < 96) {
    double vq = 0.0;
    for (int k = 0; k < 32; ++k) {
      double a = (i < 64) ? (double)C2[k*64+i] : (double)D21[k*32+(i-64)];
      double b = (j < 64) ? (double)C2[k*64+j] : (double)D21[k*32+(j-64)];
      vq += a*b;
    }
    s += EPS_Q * vq;
  }
  H[i*160+j] = s;
}

// ================= prep 3: E^-1 (GJ fp32 + 2x fp64 Newton), weight blob =================
// 1024 threads: the two fp64 64x64x64 Newton matmuls and the GJ rank-updates were
// the dominant prep cost at 256 threads (single block).
__global__ __launch_bounds__(1024, 1) void prep3(
    const float* __restrict__ Y, const float* __restrict__ B2,
    const float* __restrict__ C2, const float* __restrict__ D12,
    const float* __restrict__ D21, double* __restrict__ wsd)
{
  __shared__ float aug[64][130];
  __shared__ float sFac[64];
  __shared__ int sPiv;
  const int tid = threadIdx.x;
  double* H   = wsd + OFF_H;
  double* Ed  = wsd + OFF_E;
  double* Ei  = wsd + OFF_EI;
  double* Tm  = wsd + OFF_TMP;
  double* Tm2 = wsd + OFF_TMP2;
  double* D22d = wsd + OFF_D22;
  float* fb = (float*)(wsd + D_END);
  const double KS = 2.8853900817779268;   // 2*log2(e)

  for (int idx = tid; idx < 4096; idx += 1024) {
    int i = idx >> 6, j = idx & 63;
    double e = 0.5*(H[i*160+j] + H[(96+i)*160+(96+j)] + (double)Y[i*64+j] - (double)Y[j*64+i]);
    Ed[idx] = e;
    aug[i][j] = (float)e;
    aug[i][64+j] = (i == j) ? 1.f : 0.f;
  }
  __syncthreads();
  for (int k = 0; k < 64; ++k) {
    if (tid < 64) {
      float mv = -1.f; int mi = k;
      if (tid >= k) { mv = fabsf(aug[tid][k]); mi = tid; }
      #pragma unroll
      for (int o = 32; o; o >>= 1) {
        float ov = __shfl_xor(mv, o); int oi = __shfl_xor(mi, o);
        if (ov > mv) { mv = ov; mi = oi; }
      }
      if (tid == 0) sPiv = mi;
    }
    __syncthreads();
    int p = sPiv;
    if (p != k) for (int c = tid; c < 128; c += 1024) { float t1 = aug[k][c]; aug[k][c] = aug[p][c]; aug[p][c] = t1; }
    __syncthreads();
    float pinv = 1.0f / aug[k][k];
    if (tid < 64 && tid != k) sFac[tid] = aug[tid][k];
    __syncthreads();
    for (int c = tid; c < 128; c += 1024) aug[k][c] *= pinv;
    __syncthreads();
    for (int idx = tid; idx < 64*128; idx += 1024) {
      int r = idx >> 7, c = idx & 127;
      if (r != k) aug[r][c] -= sFac[r] * aug[k][c];
    }
    __syncthreads();
  }
  for (int idx = tid; idx < 4096; idx += 1024) Ei[idx] = (double)aug[idx >> 6][64 + (idx & 63)];
  __syncthreads();
  for (int it = 0; it < 2; ++it) {
    for (int idx = tid; idx < 4096; idx += 1024) {
      int i = idx >> 6, j = idx & 63;
      double s = (i == j) ? 2.0 : 0.0;
      for (int k = 0; k < 64; ++k) s -= Ed[i*64+k] * Ei[k*64+j];
      Tm[idx] = s;
    }
    __syncthreads();
    for (int idx = tid; idx < 4096; idx += 1024) {
      int i = idx >> 6, j = idx & 63;
      double s = 0.0;
      for (int k = 0; k < 64; ++k) s += Ei[i*64+k] * Tm[k*64+j];
      Tm2[idx] = s;
    }
    __syncthreads();
    for (int idx = tid; idx < 4096; idx += 1024) Ei[idx] = Tm2[idx];
    __syncthreads();
  }
  // WxT: k-major f4-transposed [32 chunks][64 rows][4]
  for (int idx = tid; idx < 64*128; idx += 1024) {
    int r = idx >> 7, col = idx & 127;
    double s = 0.0;
    if (col < 64)       { for (int k = 0; k < 64; ++k) s += Ei[r*64+k] * H[(96+k)*160 + col]; }
    else if (col < 96)  { int jj = col-64; for (int k = 0; k < 64; ++k) s += Ei[r*64+k] * H[(96+k)*160 + 64 + jj]; }
    else                { int jj = col-96; for (int k = 0; k < 64; ++k) s += Ei[r*64+k] * (double)B2[k*32+jj]; }
    fb[((col >> 2)*64 + r)*4 + (col & 3)] = (float)s;
  }
  // WyT: k-major f4-transposed [32 chunks][32 rows][4]; cols [C2(64)|D21(32)|D22(32)]
  for (int idx = tid; idx < 32*128; idx += 1024) {
    int r = idx >> 7, col = idx & 127;
    float v;
    if (col < 64)      v = C2[r*64 + col];
    else if (col < 96) v = D21[r*32 + (col-64)];
    else               v = (float)D22d[r*32 + (col-96)];
    fb[8192 + ((col >> 2)*32 + r)*4 + (col & 3)] = v;
  }
  // D11' (strict lower, scaled by K/Lam_i) @ 12288  -- chain runs in exp2 domain
  for (int idx = tid; idx < 1024; idx += 1024) {
    int i = idx >> 5, j = idx & 31;
    double li = 2.0 / H[(64+i)*160 + 64+i];
    fb[12288 + idx] = (j < i) ? (float)(-H[(64+i)*160 + 64+j] * li * KS) : 0.f;
  }
  // Wa = [C1 | D12] * (K/Lam_r), row-major [32][96] @ 13312
  for (int idx = tid; idx < 32*96; idx += 1024) {
    int r = idx / 96, j = idx % 96;
    double li = 2.0 / H[(64+r)*160 + 64+r];
    double v = (j < 64) ? (-H[(64+r)*160 + j] * li) : ((double)D12[r*32 + (j-64)] * li);
    fb[13312 + idx] = (float)(v * KS);
  }
}

// ================= main recurrence =================
__device__ __forceinline__ float frcp(float x) {
#if __has_builtin(__builtin_amdgcn_rcpf)
  return __builtin_amdgcn_rcpf(x);
#else
  return 1.0f / x;
#endif
}
__device__ __forceinline__ float hsum4(float4 a) { return (a.x + a.y) + (a.z + a.w); }

// E=1: wave per element, 2048 waves = 2 waves/SIMD (the round-1 E=2 experiment
// showed 1 wave/SIMD cannot hide the serial-chain latency).
// KEY CHANGE vs the 848us version: Wx (the 64x128 state-update matrix) lives in
// REGISTERS (32 f4 = 128 VGPR, loaded once from global). Previously all weights
// were re-streamed from LDS every timestep: ~48 lane-indexed ds_read_b128/wave/t
// = ~393 KB/CU/t, saturating the LDS pipe (~4.6k cyc/t at ~85 B/cyc) -- that,
// not VALU, set the 7950 cyc/t wall. Remaining LDS: Wy+Wa (28 reads/t,
// conflict-free chunk-major layout) + cheap same-address broadcasts of state.
// Chain: 6-op step in exp2 domain (weights pre-scaled by K), no clamp
// (exp2 saturates correctly through 1-2*rcp(E+1)).
__global__ __launch_bounds__(256, 2) void ren_main(
    const float* __restrict__ u_in, const float* __restrict__ x0,
    const double* __restrict__ wsd, float* __restrict__ out)
{
  __shared__ __align__(16) float sW[7168];     // Wy [32ch][32r]f4 | WaT [24ch][32r]f4
  __shared__ __align__(16) float sXU[4][132];  // per wave: x(64)|w(32)|u(32)|pad(4)
  const float* fb = (const float*)(wsd + D_END);
  const int tid = threadIdx.x;
  {
    const float4* g4 = (const float4*)fb;
    float4* s4 = (float4*)sW;
    for (int i = tid; i < 1024; i += 256) s4[i] = g4[2048 + i];   // Wy (fb f4 2048..3071)
    for (int i = tid; i < 768; i += 256) {                        // Wa: [32][24] -> [24][32]
      int r2 = i / 24, ch = i % 24;
      s4[1024 + ch*32 + r2] = g4[3328 + i];                       // fb f4 3328..4095
    }
  }
  const int wv = tid >> 6, l = tid & 63;
  const int r = l & 31, lh = l >> 5;
  const int e = blockIdx.x * 4 + wv;           // this wave's element
  float* xu = &sXU[wv][0];

  // Wx row l in registers: 32 f4 = 128 VGPR (loaded once, coalesced)
  float4 wx[32];
  {
    const float4* WxG = (const float4*)fb;
    #pragma unroll
    for (int c = 0; c < 32; ++c) wx[c] = WxG[(c << 6) + l];
  }
  // D11' row r (strict lower, K/Lam-scaled): 32 VGPR
  float d11[32];
  {
    const float4* DG = (const float4*)(fb + 12288);
    #pragma unroll
    for (int c = 0; c < 8; ++c) {
      float4 dv = DG[r*8 + c];
      d11[4*c+0] = dv.x; d11[4*c+1] = dv.y; d11[4*c+2] = dv.z; d11[4*c+3] = dv.w;
    }
  }
  // x0 and u(t=0)
  xu[l] = x0[(size_t)e*64 + l];
  xu[96 + r] = u_in[(size_t)e*8192 + r];       // both halves write same value
  __syncthreads();   // weights staged (once, outside t-loop)

  const float4* xu4  = (const float4*)xu;      // 33 f4: x 0-15 | w 16-23 | u 24-31
  const float4* WyT4 = (const float4*)sW;              // [(ch<<5)+r]
  const float4* WaT4 = (const float4*)sW + 1024;       // [(lh*12+c)*32 + r]
  const float* uG = u_in + (size_t)e * 8192;
  float* oG = out + (size_t)e * 8192;

#define FMA4(A, W, XV) \
  A.x = fmaf(W.x, XV.x, A.x); A.y = fmaf(W.y, XV.y, A.y); \
  A.z = fmaf(W.z, XV.z, A.z); A.w = fmaf(W.w, XV.w, A.w);

  for (int t = 0; t < 256; ++t) {
    const int tn = (t < 255) ? (t + 1) : 255;
    float unext = uG[tn*32 + r];               // prefetch u_{t+1}
    // ---- A: a_r (K-scaled), k-split across halves, combine via shfl ----
    float4 sA = make_float4(0.f, 0.f, 0.f, 0.f);
    #pragma unroll
    for (int c = 0; c < 12; ++c) {
      int ch = lh*12 + c;
      int xi = (ch < 16) ? ch : (ch + 8);      // u chunks at f4 24..31
      float4 xv = xu4[xi]; float4 wv4 = WaT4[ch*32 + r];
      FMA4(sA, wv4, xv)
    }
    float a = hsum4(sA);
    a += __shfl_xor(a, 32);                    // all 64 lanes: K*a for row r
    // ---- X partial: x chunks + u chunks (chain-independent scheduler filler) ----
    float4 P4 = make_float4(0.f, 0.f, 0.f, 0.f);
    #pragma unroll
    for (int c = 0; c < 16; ++c) { float4 xv = xu4[c]; FMA4(P4, wx[c], xv) }
    #pragma unroll
    for (int c = 24; c < 32; ++c) { float4 xv = xu4[c]; FMA4(P4, wx[c], xv) }
    // ---- Y partial: D22.u chunks (lh0: 24..27, lh1: 28..31) ----
    float4 Q4 = make_float4(0.f, 0.f, 0.f, 0.f);
    #pragma unroll
    for (int c = 0; c < 4; ++c) {
      int ch = 24 + lh*4 + c;
      float4 xv = xu4[ch]; float4 wv4 = WyT4[(ch << 5) + r];
      FMA4(Q4, wv4, xv)
    }
    // ---- serial tanh forward-substitution (6-op step, exp2 domain) ----
    float v = a;
    #pragma unroll
    for (int j = 0; j < 31; ++j) {
      float E = __builtin_exp2f(v);
      float w = fmaf(-2.f, frcp(E + 1.f), 1.f);
      float b = __int_as_float(__builtin_amdgcn_readlane(__float_as_int(w), j));
      v = fmaf(d11[j], b, v);
    }
    float Ef = __builtin_exp2f(v);
    float myw = fmaf(-2.f, frcp(Ef + 1.f), 1.f);
    xu[64 + r] = myw;                          // both halves same value
    // ---- X final: w chunks 16..23, then store xn ----
    #pragma unroll
    for (int c = 16; c < 24; ++c) { float4 xv = xu4[c]; FMA4(P4, wx[c], xv) }
    xu[l] = hsum4(P4);                         // xn row l
    // ---- Y final: chunks lh*12 .. lh*12+11 (xn + w), combine via shfl ----
    #pragma unroll
    for (int c = 0; c < 12; ++c) {
      int ch = lh*12 + c;
      float4 xv = xu4[ch]; float4 wv4 = WyT4[(ch << 5) + r];
      FMA4(Q4, wv4, xv)
    }
    float y = hsum4(Q4);
    y += __shfl_xor(y, 32);
    if (l < 32) oG[t*32 + l] = y;              // contiguous 128 B
    xu[96 + r] = unext;                        // u_{t+1} (u_t fully consumed)
  }
#undef FMA4
}

// ================= launch =================
extern "C" void kernel_launch(void* const* d_in, const int* in_sizes, int n_in,
                              void* d_out, int out_size, void* d_ws, size_t ws_size,
                              hipStream_t stream)
{
  const float* u_in = (const float*)d_in[0];
  const float* x0   = (const float*)d_in[1];
  const float* X    = (const float*)d_in[2];
  const float* Y    = (const float*)d_in[3];
  const float* B2   = (const float*)d_in[4];
  const float* C2   = (const float*)d_in[5];
  const float* D12  = (const float*)d_in[6];
  const float* L    = (const float*)d_in[7];   // D22_L
  const float* U    = (const float*)d_in[8];   // D22_U
  const float* D21  = (const float*)d_in[9];
  const float* gam  = (const float*)d_in[10];
  double* wsd = (double*)d_ws;
  float* out = (float*)d_out;

  hipLaunchKernelGGL(prep1, dim3(1), dim3(256), 0, stream, B2, C2, D12, L, U, D21, gam, wsd);
  hipLaunchKernelGGL(prep2, dim3(100), dim3(256), 0, stream, X, C2, D21, wsd);
  hipLaunchKernelGGL(prep3, dim3(1), dim3(1024), 0, stream, Y, B2, C2, D12, D21, wsd);
  hipLaunchKernelGGL(ren_main, dim3(512), dim3(256), 0, stream, u_in, x0, wsd, out);
}

// Round 3
// 1658.245 us; speedup vs baseline: 1.0412x; 1.0102x over previous
//
#include <hip/hip_runtime.h>
#include <math.h>

// ---------------- dims / constants ----------------
#define EPS_Q 1e-4
#define TOLC  1e-3

// ws layout: doubles first
#define OFF_D22   0        // [32][32]
#define OFF_RINV  1024     // [32][32]
#define OFF_VR    2048     // [160][32]
#define OFF_T1    7168     // [160][32]
#define OFF_H     12288    // [160][160]
#define OFF_E     37888    // [64][64]
#define OFF_EI    41984    // [64][64]
#define OFF_TMP   46080    // [64][64]
#define OFF_TMP2  50176    // [64][64]
#define D_END     54272    // doubles
// float blob after doubles (byte offset 434176, 16B aligned):
// F_WXT  = 0      : Wx k-major f4-transposed [32 chunks][64 rows][4] = 8192 floats
// F_WYT  = 8192   : Wy k-major f4-transposed [32 chunks][32 rows][4] = 4096 floats
// F_D11  = 12288  : [32][32] strictly-lower, pre-scaled by K/Lam_i   = 1024
// F_WA   = 13312  : [32][96] rows [C1(64)|D12(32)] * (K/Lam_r)       = 3072
// K = 2*log2(e): chain state v lives in exp2 domain (saves ops on critical path)

// ================= prep 1: D22, R_cal^-1, vec_r, T1 =================
__global__ __launch_bounds__(256, 1) void prep1(
    const float* __restrict__ B2, const float* __restrict__ C2,
    const float* __restrict__ D12, const float* __restrict__ L,
    const float* __restrict__ U, const float* __restrict__ D21,
    const float* __restrict__ gam, double* __restrict__ wsd)
{
  __shared__ double aug[32][65];
  __shared__ double sFac[32];
  __shared__ int sPiv;
  const int tid = threadIdx.x;
  const double g = (double)gam[0];
  double* D22d = wsd + OFF_D22;

  for (int idx = tid; idx < 1024; idx += 256) {
    int i = idx >> 5, j = idx & 31;
    double s = (i == j) ? (g + 1.0) : 0.0;
    for (int k = 0; k < 32; ++k) s += (double)L[k*32+i] * (double)L[k*32+j];
    s += (double)U[i*32+j] - (double)U[j*32+i];
    D22d[idx] = s;
  }
  __syncthreads();
  for (int idx = tid; idx < 1024; idx += 256) {
    int i = idx >> 5, j = idx & 31;
    double s = (i == j) ? (-2.0 * g) : 0.0;
    s += D22d[i*32+j] + D22d[j*32+i];
    double q = 0.0;
    for (int k = 0; k < 32; ++k) q += D22d[k*32+i] * D22d[k*32+j];
    aug[i][j] = s - EPS_Q * q;
    aug[i][32+j] = (i == j) ? 1.0 : 0.0;
  }
  __syncthreads();
  for (int k = 0; k < 32; ++k) {
    if (tid < 64) {
      float mv = -1.f; int mi = k;
      if (tid < 32 && tid >= k) { mv = (float)fabs(aug[tid][k]); mi = tid; }
      #pragma unroll
      for (int o = 32; o; o >>= 1) {
        float ov = __shfl_xor(mv, o); int oi = __shfl_xor(mi, o);
        if (ov > mv) { mv = ov; mi = oi; }
      }
      if (tid == 0) sPiv = mi;
    }
    __syncthreads();
    int p = sPiv;
    if (p != k) for (int c = tid; c < 64; c += 256) { double t1 = aug[k][c]; aug[k][c] = aug[p][c]; aug[p][c] = t1; }
    __syncthreads();
    double pinv = 1.0 / aug[k][k];
    if (tid < 32 && tid != k) sFac[tid] = aug[tid][k];
    __syncthreads();
    for (int c = tid; c < 64; c += 256) aug[k][c] *= pinv;
    __syncthreads();
    for (int idx = tid; idx < 2048; idx += 256) {
      int r = idx >> 6, c = idx & 63;
      if (r != k) aug[r][c] -= sFac[r] * aug[k][c];
    }
    __syncthreads();
  }
  double* Rinv = wsd + OFF_RINV;
  for (int idx = tid; idx < 1024; idx += 256) Rinv[idx] = aug[idx >> 5][32 + (idx & 31)];

  double* vr = wsd + OFF_VR;
  for (int idx = tid; idx < 64*32; idx += 256) {
    int p = idx >> 5, k = idx & 31;
    double q = 0.0;
    for (int m = 0; m < 32; ++m) q += D22d[m*32+k] * (double)C2[m*64+p];
    vr[p*32+k] = (double)C2[k*64+p] - EPS_Q * q;
  }
  for (int idx = tid; idx < 32*32; idx += 256) {
    int p = idx >> 5, k = idx & 31;
    double q = 0.0;
    for (int m = 0; m < 32; ++m) q += D22d[m*32+k] * (double)D21[m*32+p];
    vr[(64+p)*32+k] = (double)D21[k*32+p] - EPS_Q * q - (double)D12[p*32+k];
  }
  for (int idx = tid; idx < 64*32; idx += 256) {
    int p = idx >> 5, k = idx & 31;
    vr[(96+p)*32+k] = (double)B2[p*32+k];
  }
  __syncthreads();
  double* T1 = wsd + OFF_T1;
  for (int idx = tid; idx < 160*32; idx += 256) {
    int p = idx >> 5, k2 = idx & 31;
    double s = 0.0;
    for (int k = 0; k < 32; ++k) s += vr[p*32+k] * Rinv[k*32+k2];
    T1[idx] = s;
  }
}

// ================= prep 2: H = X^T X + tol I + psi_r - psi_q =================
__global__ __launch_bounds__(256, 1) void prep2(
    const float* __restrict__ X, const float* __restrict__ C2,
    const float* __restrict__ D21, double* __restrict__ wsd)
{
  const double* vr = wsd + OFF_VR;
  const double* T1 = wsd + OFF_T1;
  double* H = wsd + OFF_H;
  int bi = blockIdx.x / 10, bj = blockIdx.x % 10;
  int i = bi*16 + (threadIdx.x >> 4);
  int j = bj*16 + (threadIdx.x & 15);
  double s = (i == j) ? TOLC : 0.0;
  for (int k = 0; k < 160; ++k) s += (double)X[k*160+i] * (double)X[k*160+j];
  double pr = 0.0;
  for (int k = 0; k < 32; ++k) pr += T1[i*32+k] * vr[j*32+k];
  s += pr;
  if (i < 96 && j < 96) {
    double vq = 0.0;
    for (int k = 0; k < 32; ++k) {
      double a = (i < 64) ? (double)C2[k*64+i] : (double)D21[k*32+(i-64)];
      double b = (j < 64) ? (double)C2[k*64+j] : (double)D21[k*32+(j-64)];
      vq += a*b;
    }
    s += EPS_Q * vq;
  }
  H[i*160+j] = s;
}

// ================= prep 3: E^-1 (GJ fp32 + 2x fp64 Newton), weight blob =================
__global__ __launch_bounds__(1024, 1) void prep3(
    const float* __restrict__ Y, const float* __restrict__ B2,
    const float* __restrict__ C2, const float* __restrict__ D12,
    const float* __restrict__ D21, double* __restrict__ wsd)
{
  __shared__ float aug[64][130];
  __shared__ float sFac[64];
  __shared__ int sPiv;
  const int tid = threadIdx.x;
  double* H   = wsd + OFF_H;
  double* Ed  = wsd + OFF_E;
  double* Ei  = wsd + OFF_EI;
  double* Tm  = wsd + OFF_TMP;
  double* Tm2 = wsd + OFF_TMP2;
  double* D22d = wsd + OFF_D22;
  float* fb = (float*)(wsd + D_END);
  const double KS = 2.8853900817779268;   // 2*log2(e)

  for (int idx = tid; idx < 4096; idx += 1024) {
    int i = idx >> 6, j = idx & 63;
    double e = 0.5*(H[i*160+j] + H[(96+i)*160+(96+j)] + (double)Y[i*64+j] - (double)Y[j*64+i]);
    Ed[idx] = e;
    aug[i][j] = (float)e;
    aug[i][64+j] = (i == j) ? 1.f : 0.f;
  }
  __syncthreads();
  for (int k = 0; k < 64; ++k) {
    if (tid < 64) {
      float mv = -1.f; int mi = k;
      if (tid >= k) { mv = fabsf(aug[tid][k]); mi = tid; }
      #pragma unroll
      for (int o = 32; o; o >>= 1) {
        float ov = __shfl_xor(mv, o); int oi = __shfl_xor(mi, o);
        if (ov > mv) { mv = ov; mi = oi; }
      }
      if (tid == 0) sPiv = mi;
    }
    __syncthreads();
    int p = sPiv;
    if (p != k) for (int c = tid; c < 128; c += 1024) { float t1 = aug[k][c]; aug[k][c] = aug[p][c]; aug[p][c] = t1; }
    __syncthreads();
    float pinv = 1.0f / aug[k][k];
    if (tid < 64 && tid != k) sFac[tid] = aug[tid][k];
    __syncthreads();
    for (int c = tid; c < 128; c += 1024) aug[k][c] *= pinv;
    __syncthreads();
    for (int idx = tid; idx < 64*128; idx += 1024) {
      int r = idx >> 7, c = idx & 127;
      if (r != k) aug[r][c] -= sFac[r] * aug[k][c];
    }
    __syncthreads();
  }
  for (int idx = tid; idx < 4096; idx += 1024) Ei[idx] = (double)aug[idx >> 6][64 + (idx & 63)];
  __syncthreads();
  for (int it = 0; it < 2; ++it) {
    for (int idx = tid; idx < 4096; idx += 1024) {
      int i = idx >> 6, j = idx & 63;
      double s = (i == j) ? 2.0 : 0.0;
      for (int k = 0; k < 64; ++k) s -= Ed[i*64+k] * Ei[k*64+j];
      Tm[idx] = s;
    }
    __syncthreads();
    for (int idx = tid; idx < 4096; idx += 1024) {
      int i = idx >> 6, j = idx & 63;
      double s = 0.0;
      for (int k = 0; k < 64; ++k) s += Ei[i*64+k] * Tm[k*64+j];
      Tm2[idx] = s;
    }
    __syncthreads();
    for (int idx = tid; idx < 4096; idx += 1024) Ei[idx] = Tm2[idx];
    __syncthreads();
  }
  // WxT: k-major f4-transposed [32 chunks][64 rows][4]
  for (int idx = tid; idx < 64*128; idx += 1024) {
    int r = idx >> 7, col = idx & 127;
    double s = 0.0;
    if (col < 64)       { for (int k = 0; k < 64; ++k) s += Ei[r*64+k] * H[(96+k)*160 + col]; }
    else if (col < 96)  { int jj = col-64; for (int k = 0; k < 64; ++k) s += Ei[r*64+k] * H[(96+k)*160 + 64 + jj]; }
    else                { int jj = col-96; for (int k = 0; k < 64; ++k) s += Ei[r*64+k] * (double)B2[k*32+jj]; }
    fb[((col >> 2)*64 + r)*4 + (col & 3)] = (float)s;
  }
  // WyT: k-major f4-transposed [32 chunks][32 rows][4]; cols [C2(64)|D21(32)|D22(32)]
  for (int idx = tid; idx < 32*128; idx += 1024) {
    int r = idx >> 7, col = idx & 127;
    float v;
    if (col < 64)      v = C2[r*64 + col];
    else if (col < 96) v = D21[r*32 + (col-64)];
    else               v = (float)D22d[r*32 + (col-96)];
    fb[8192 + ((col >> 2)*32 + r)*4 + (col & 3)] = v;
  }
  // D11' (strict lower, scaled by K/Lam_i) @ 12288  -- chain runs in exp2 domain
  for (int idx = tid; idx < 1024; idx += 1024) {
    int i = idx >> 5, j = idx & 31;
    double li = 2.0 / H[(64+i)*160 + 64+i];
    fb[12288 + idx] = (j < i) ? (float)(-H[(64+i)*160 + 64+j] * li * KS) : 0.f;
  }
  // Wa = [C1 | D12] * (K/Lam_r), row-major [32][96] @ 13312
  for (int idx = tid; idx < 32*96; idx += 1024) {
    int r = idx / 96, j = idx % 96;
    double li = 2.0 / H[(64+r)*160 + 64+r];
    double v = (j < 64) ? (-H[(64+r)*160 + j] * li) : ((double)D12[r*32 + (j-64)] * li);
    fb[13312 + idx] = (float)(v * KS);
  }
}

// ================= main recurrence =================
__device__ __forceinline__ float frcp(float x) {
#if __has_builtin(__builtin_amdgcn_rcpf)
  return __builtin_amdgcn_rcpf(x);
#else
  return 1.0f / x;
#endif
}
__device__ __forceinline__ float hsum4(float4 a) { return (a.x + a.y) + (a.z + a.w); }

// E=1: wave per element, 2048 waves = 2 waves/SIMD.
// Wx (64x128 state-update matrix) lives in REGISTERS: 32 f4 = 128 VGPR/lane.
// ROUND-2 LESSON: __launch_bounds__(256,2) alone let the allocator target its
// default (higher) occupancy -> it kept only 128 VGPRs and SPILLED wx to
// scratch (WRITE_SIZE 65536->74240 KB, VALUBusy 54%, dur 1154us).
// amdgpu_waves_per_eu(2,2) pins the register budget to exactly 2 waves/EU
// (256 VGPR) -- the grid only supplies 2 waves/SIMD anyway, so this costs
// nothing and stops the spill. Verification gate: VGPR_Count must be >128 and
// WRITE_SIZE must return to exactly 65536 KB.
__global__ __launch_bounds__(256)
__attribute__((amdgpu_waves_per_eu(2, 2)))
void ren_main(
    const float* __restrict__ u_in, const float* __restrict__ x0,
    const double* __restrict__ wsd, float* __restrict__ out)
{
  __shared__ __align__(16) float sW[7168];     // Wy [32ch][32r]f4 | WaT [24ch][32r]f4
  __shared__ __align__(16) float sXU[4][132];  // per wave: x(64)|w(32)|u(32)|pad(4)
  const float* fb = (const float*)(wsd + D_END);
  const int tid = threadIdx.x;
  {
    const float4* g4 = (const float4*)fb;
    float4* s4 = (float4*)sW;
    for (int i = tid; i < 1024; i += 256) s4[i] = g4[2048 + i];   // Wy (fb f4 2048..3071)
    for (int i = tid; i < 768; i += 256) {                        // Wa: [32][24] -> [24][32]
      int r2 = i / 24, ch = i % 24;
      s4[1024 + ch*32 + r2] = g4[3328 + i];                       // fb f4 3328..4095
    }
  }
  const int wv = tid >> 6, l = tid & 63;
  const int r = l & 31, lh = l >> 5;
  const int e = blockIdx.x * 4 + wv;           // this wave's element
  float* xu = &sXU[wv][0];

  // Wx row l in registers: 32 f4 = 128 VGPR (loaded once, coalesced)
  float4 wx[32];
  {
    const float4* WxG = (const float4*)fb;
    #pragma unroll
    for (int c = 0; c < 32; ++c) wx[c] = WxG[(c << 6) + l];
  }
  // D11' row r (strict lower, K/Lam-scaled): 32 VGPR
  float d11[32];
  {
    const float4* DG = (const float4*)(fb + 12288);
    #pragma unroll
    for (int c = 0; c < 8; ++c) {
      float4 dv = DG[r*8 + c];
      d11[4*c+0] = dv.x; d11[4*c+1] = dv.y; d11[4*c+2] = dv.z; d11[4*c+3] = dv.w;
    }
  }
  // x0 and u(t=0)
  xu[l] = x0[(size_t)e*64 + l];
  xu[96 + r] = u_in[(size_t)e*8192 + r];       // both halves write same value
  __syncthreads();   // weights staged (once, outside t-loop)

  const float4* xu4  = (const float4*)xu;      // 33 f4: x 0-15 | w 16-23 | u 24-31
  const float4* WyT4 = (const float4*)sW;              // [(ch<<5)+r]
  const float4* WaT4 = (const float4*)sW + 1024;       // [(lh*12+c)*32 + r]
  const float* uG = u_in + (size_t)e * 8192;
  float* oG = out + (size_t)e * 8192;

#define FMA4(A, W, XV) \
  A.x = fmaf(W.x, XV.x, A.x); A.y = fmaf(W.y, XV.y, A.y); \
  A.z = fmaf(W.z, XV.z, A.z); A.w = fmaf(W.w, XV.w, A.w);

  for (int t = 0; t < 256; ++t) {
    const int tn = (t < 255) ? (t + 1) : 255;
    float unext = uG[tn*32 + r];               // prefetch u_{t+1}
    // ---- A: a_r (K-scaled), k-split across halves, combine via shfl ----
    float4 sA = make_float4(0.f, 0.f, 0.f, 0.f);
    #pragma unroll
    for (int c = 0; c < 12; ++c) {
      int ch = lh*12 + c;
      int xi = (ch < 16) ? ch : (ch + 8);      // u chunks at f4 24..31
      float4 xv = xu4[xi]; float4 wv4 = WaT4[ch*32 + r];
      FMA4(sA, wv4, xv)
    }
    float a = hsum4(sA);
    a += __shfl_xor(a, 32);                    // all 64 lanes: K*a for row r
    // ---- X partial: x chunks + u chunks (chain-independent scheduler filler) ----
    float4 P4 = make_float4(0.f, 0.f, 0.f, 0.f);
    #pragma unroll
    for (int c = 0; c < 16; ++c) { float4 xv = xu4[c]; FMA4(P4, wx[c], xv) }
    #pragma unroll
    for (int c = 24; c < 32; ++c) { float4 xv = xu4[c]; FMA4(P4, wx[c], xv) }
    // ---- Y partial: D22.u chunks (lh0: 24..27, lh1: 28..31) ----
    float4 Q4 = make_float4(0.f, 0.f, 0.f, 0.f);
    #pragma unroll
    for (int c = 0; c < 4; ++c) {
      int ch = 24 + lh*4 + c;
      float4 xv = xu4[ch]; float4 wv4 = WyT4[(ch << 5) + r];
      FMA4(Q4, wv4, xv)
    }
    // ---- serial tanh forward-substitution (6-op step, exp2 domain) ----
    float v = a;
    #pragma unroll
    for (int j = 0; j < 31; ++j) {
      float E = __builtin_exp2f(v);
      float w = fmaf(-2.f, frcp(E + 1.f), 1.f);
      float b = __int_as_float(__builtin_amdgcn_readlane(__float_as_int(w), j));
      v = fmaf(d11[j], b, v);
    }
    float Ef = __builtin_exp2f(v);
    float myw = fmaf(-2.f, frcp(Ef + 1.f), 1.f);
    xu[64 + r] = myw;                          // both halves same value
    // ---- X final: w chunks 16..23, then store xn ----
    #pragma unroll
    for (int c = 16; c < 24; ++c) { float4 xv = xu4[c]; FMA4(P4, wx[c], xv) }
    xu[l] = hsum4(P4);                         // xn row l
    // ---- Y final: chunks lh*12 .. lh*12+11 (xn + w), combine via shfl ----
    #pragma unroll
    for (int c = 0; c < 12; ++c) {
      int ch = lh*12 + c;
      float4 xv = xu4[ch]; float4 wv4 = WyT4[(ch << 5) + r];
      FMA4(Q4, wv4, xv)
    }
    float y = hsum4(Q4);
    y += __shfl_xor(y, 32);
    if (l < 32) oG[t*32 + l] = y;              // contiguous 128 B
    xu[96 + r] = unext;                        // u_{t+1} (u_t fully consumed)
  }
#undef FMA4
}

// ================= launch =================
extern "C" void kernel_launch(void* const* d_in, const int* in_sizes, int n_in,
                              void* d_out, int out_size, void* d_ws, size_t ws_size,
                              hipStream_t stream)
{
  const float* u_in = (const float*)d_in[0];
  const float* x0   = (const float*)d_in[1];
  const float* X    = (const float*)d_in[2];
  const float* Y    = (const float*)d_in[3];
  const float* B2   = (const float*)d_in[4];
  const float* C2   = (const float*)d_in[5];
  const float* D12  = (const float*)d_in[6];
  const float* L    = (const float*)d_in[7];   // D22_L
  const float* U    = (const float*)d_in[8];   // D22_U
  const float* D21  = (const float*)d_in[9];
  const float* gam  = (const float*)d_in[10];
  double* wsd = (double*)d_ws;
  float* out = (float*)d_out;

  hipLaunchKernelGGL(prep1, dim3(1), dim3(256), 0, stream, B2, C2, D12, L, U, D21, gam, wsd);
  hipLaunchKernelGGL(prep2, dim3(100), dim3(256), 0, stream, X, C2, D21, wsd);
  hipLaunchKernelGGL(prep3, dim3(1), dim3(1024), 0, stream, Y, B2, C2, D12, D21, wsd);
  hipLaunchKernelGGL(ren_main, dim3(512), dim3(256), 0, stream, u_in, x0, wsd, out);
}